// Round 9
// baseline (1330.543 us; speedup 1.0000x reference)
//
#include <hip/hip_runtime.h>
#include <math.h>

// Problem constants
#define BB 8
#define MM 2048
#define KM 1024
#define DD 256
#define HH 4
#define HD 64
#define NLAYER 2
#define BN (BB*KM)        // 8192 rows per "decoder half"
#define N2 (2*BN)         // 16384 rows d0||d1
#define CG_ITERS 6
#define MS 76             // mha LDS row stride (38 dwords == 6 mod 32 -> conflict-free)

typedef __bf16 bf16;
typedef __bf16 bf16x8 __attribute__((ext_vector_type(8)));
typedef __bf16 bf16x4 __attribute__((ext_vector_type(4)));
typedef __bf16 bf16x2 __attribute__((ext_vector_type(2)));
typedef short  short4v __attribute__((ext_vector_type(4)));
typedef float  floatx4 __attribute__((ext_vector_type(4)));
#define MFMA16(a,b,c) __builtin_amdgcn_mfma_f32_16x16x32_bf16(a,b,c,0,0,0)

// K=16 bf16 MFMA (PV stage: S^T C-frag == its B-operand layout).
#if defined(__HIP_DEVICE_COMPILE__)
  #if __has_builtin(__builtin_amdgcn_mfma_f32_16x16x16bf16_1k)
    #define MFMA1K(a,b,c) __builtin_amdgcn_mfma_f32_16x16x16bf16_1k(a,b,c,0,0,0)
  #else
    #error "device pass lacks mfma_f32_16x16x16bf16_1k"
  #endif
#else
  #define MFMA1K(a,b,c) (c)   /* host stub, never executed */
#endif

__device__ __forceinline__ float softplusf(float x) {
  return fmaxf(x, 0.f) + log1pf(expf(-fabsf(x)));
}

__device__ __forceinline__ short4v pack4(float a, float b, float c, float d) {
  bf16x4 v = {(bf16)a,(bf16)b,(bf16)c,(bf16)d};
  short4v s;
  __builtin_memcpy(&s, &v, 8);
  return s;
}

// stage 8 elements (convert to bf16 if needed), 16B LDS store
__device__ __forceinline__ void stage8(bf16* dst, const float* src) {
  float4 a = *(const float4*)src;
  float4 b = *(const float4*)(src + 4);
  bf16x8 v = { (bf16)a.x,(bf16)a.y,(bf16)a.z,(bf16)a.w,
               (bf16)b.x,(bf16)b.y,(bf16)b.z,(bf16)b.w };
  *(bf16x8*)dst = v;
}
__device__ __forceinline__ void stage8(bf16* dst, const bf16* src) {
  *(uint4*)dst = *(const uint4*)src;
}

// ---------------- gather ----------------
__global__ __launch_bounds__(256) void gather_kernel(
    const float* __restrict__ fa, const float* __restrict__ fb,
    const int* __restrict__ matches, const float* __restrict__ ka,
    const float* __restrict__ kb, float* __restrict__ F,
    float* __restrict__ xy0, float* __restrict__ xy1)
{
  int si = blockIdx.x;
  int s  = si >> 10;
  int t  = threadIdx.x;
  int ia = matches[(size_t)si*2+0];
  int ib = matches[(size_t)si*2+1];
  F[(size_t)si*DD + t] = fb[((size_t)s*MM + ib)*DD + t]
                       - fa[((size_t)s*MM + ia)*DD + t];
  if (t == 0) {
    xy0[(size_t)si*2+0] = ka[((size_t)s*MM + ia)*2+0];
    xy0[(size_t)si*2+1] = ka[((size_t)s*MM + ia)*2+1];
    xy1[(size_t)si*2+0] = kb[((size_t)s*MM + ib)*2+0];
    xy1[(size_t)si*2+1] = kb[((size_t)s*MM + ib)*2+1];
  }
}

// ---------------- positional encoding ----------------
__global__ __launch_bounds__(64) void posenc_kernel(
    const float* __restrict__ xy, const float* __restrict__ Wr,
    float* __restrict__ enc)
{
  int si = blockIdx.x; int s = si >> 10, i = si & 1023;
  int d = threadIdx.x; int p = d >> 1;
  float x = xy[(size_t)si*2], y = xy[(size_t)si*2+1];
  float pr = Wr[p*2]*x + Wr[p*2+1]*y;
  enc[(((size_t)s*2+0)*KM + i)*HD + d] = cosf(pr);
  enc[(((size_t)s*2+1)*KM + i)*HD + d] = sinf(pr);
}

// ---------------- Kmat (bf16) + rowsum ----------------
__global__ __launch_bounds__(256) void kmat_kernel(
    const float* __restrict__ xy0, const float* __restrict__ beta_ptr,
    bf16* __restrict__ Km, float* __restrict__ rowsum)
{
  __shared__ float red[256];
  int si = blockIdx.x; int s = si >> 10;
  int t = threadIdx.x;
  float beta_r = softplusf(beta_ptr[0]);
  float xi = xy0[(size_t)si*2], yi = xy0[(size_t)si*2+1];
  const float* xys = xy0 + (size_t)s*KM*2;
  float sum = 0.f;
  for (int jj = 0; jj < 4; ++jj) {
    int j = jj*256 + t;
    float dx = xi - xys[j*2], dy = yi - xys[j*2+1];
    float v = expf(-beta_r*(dx*dx + dy*dy));
    bf16 vb = (bf16)v;
    Km[(size_t)si*KM + j] = vb;
    sum += (float)vb;
  }
  red[t] = sum; __syncthreads();
  for (int s2 = 128; s2 > 0; s2 >>= 1) { if (t < s2) red[t] += red[t+s2]; __syncthreads(); }
  if (t == 0) rowsum[si] = red[0] + 1e-6f;
}

// ---------------- MFMA GEMM, tile 128xNT (NT=128 or 64), BK=64 ----------------
// C = [A1|A2] @ Wsel.T, epilogue (v+bias)*scale (+resid).
// WPERM: W row index perm(j)=(j&255)*3+(j>>8)  (qkv channel de-interleave)
// DUALW: cols [0,256) from W/bias/scale, cols [256,512) from Wb/biasb/scaleb
template<int NT, int WPERM, int DUALW,
         typename TA1, typename TA2, typename TW, typename TO>
__global__ __launch_bounds__(256) void mm_kernel(
    const TA1* __restrict__ A1, const TA2* __restrict__ A2, int K1, int K,
    const TW* __restrict__ W, const float* __restrict__ bias,
    const TW* __restrict__ Wb, const float* __restrict__ biasb,
    TO* __restrict__ C, int O, float scale, float scaleb,
    const float* __restrict__ resid)
{
  __shared__ __align__(16) bf16 Al[128*72];
  __shared__ __align__(16) bf16 Wl[NT*72];
  constexpr int MB = (NT == 128) ? 4 : 2;
  int tid = threadIdx.x;
  int row0 = blockIdx.x*128, col0 = blockIdx.y*NT;
  int lane = tid & 63, w = tid >> 6;
  int wr = (NT == 128) ? (w>>1)*64 : w*32;
  int wc = (NT == 128) ? (w&1)*64 : 0;
  int lm = lane & 15, lq = lane >> 4;
  floatx4 acc[MB][4];
#pragma unroll
  for (int mb = 0; mb < MB; ++mb)
#pragma unroll
    for (int nb = 0; nb < 4; ++nb) acc[mb][nb] = (floatx4){0.f,0.f,0.f,0.f};
  for (int k0 = 0; k0 < K; k0 += 64) {
#pragma unroll
    for (int p = 0; p < 4; ++p) {
      int idx = p*256 + tid;
      int row = idx >> 3, c8 = (idx & 7)*8;
      if (k0 < K1) stage8(&Al[row*72 + c8], &A1[(size_t)(row0+row)*K1 + k0 + c8]);
      else         stage8(&Al[row*72 + c8], &A2[(size_t)(row0+row)*(K-K1) + (k0-K1) + c8]);
    }
#pragma unroll
    for (int p = 0; p < NT/32; ++p) {
      int idx = p*256 + tid;
      int row = idx >> 3, c8 = (idx & 7)*8;
      int wg = col0 + row;
      const TW* wsrc; int wrow;
      if (DUALW && wg >= 256) { wsrc = Wb; wrow = wg - 256; }
      else { wsrc = W; wrow = WPERM ? ((wg & 255)*3 + (wg >> 8)) : wg; }
      stage8(&Wl[row*72 + c8], &wsrc[(size_t)wrow*K + k0 + c8]);
    }
    __syncthreads();
    bf16x8 af[MB][2], bfr[4][2];
#pragma unroll
    for (int mb = 0; mb < MB; ++mb) {
      af[mb][0] = *(bf16x8*)&Al[(wr + mb*16 + lm)*72 + lq*8];
      af[mb][1] = *(bf16x8*)&Al[(wr + mb*16 + lm)*72 + 32 + lq*8];
    }
#pragma unroll
    for (int nb = 0; nb < 4; ++nb) {
      bfr[nb][0] = *(bf16x8*)&Wl[(wc + nb*16 + lm)*72 + lq*8];
      bfr[nb][1] = *(bf16x8*)&Wl[(wc + nb*16 + lm)*72 + 32 + lq*8];
    }
#pragma unroll
    for (int mb = 0; mb < MB; ++mb)
#pragma unroll
      for (int nb = 0; nb < 4; ++nb) {
        acc[mb][nb] = MFMA16(af[mb][0], bfr[nb][0], acc[mb][nb]);
        acc[mb][nb] = MFMA16(af[mb][1], bfr[nb][1], acc[mb][nb]);
      }
    __syncthreads();
  }
#pragma unroll
  for (int mb = 0; mb < MB; ++mb) {
#pragma unroll
    for (int nb = 0; nb < 4; ++nb) {
#pragma unroll
      for (int r = 0; r < 4; ++r) {
        int grow = row0 + wr + mb*16 + lq*4 + r;
        int gcol = col0 + wc + nb*16 + lm;
        float v = acc[mb][nb][r];
        float bv = 0.f, scl = scale;
        if (DUALW && gcol >= 256) {
          if (biasb) bv = biasb[gcol - 256];
          scl = scaleb;
        } else if (bias) {
          bv = bias[WPERM ? ((gcol & 255)*3 + (gcol >> 8)) : gcol];
        }
        v = (v + bv) * scl;
        if (resid) v += resid[(size_t)grow*O + gcol];
        C[(size_t)grow*O + gcol] = (TO)v;
      }
    }
  }
}

// ---------------- MFMA matvec-GEMM, 64x64 tile, BK=64, batched over z --------
template<typename TA, typename TW, typename TO>
__global__ __launch_bounds__(256) void mv64_kernel(
    const TA* __restrict__ A, int K, const TW* __restrict__ W,
    TO* __restrict__ C, int O,
    const float* __restrict__ resid, const float* __restrict__ lam_ptr,
    const float* __restrict__ rowdiv, float* __restrict__ dotout,
    long zsA, long zsW, long zsC, long zsR)
{
  __shared__ __align__(16) bf16 Al[64*72];
  __shared__ __align__(16) bf16 Wl[64*72];
  int tid = threadIdx.x;
  int z = blockIdx.z;
  const TA* Az = A + (size_t)z*zsA;
  const TW* Wz = W + (size_t)z*zsW;
  TO* Cz = C + (size_t)z*zsC;
  const float* Rz = resid ? (resid + (size_t)z*zsR) : (const float*)0;
  int row0 = blockIdx.x*64, col0 = blockIdx.y*64;
  int lane = tid & 63, w = tid >> 6;
  int wr = (w>>1)*32, wc = (w&1)*32;
  int lm = lane & 15, lq = lane >> 4;
  floatx4 acc[2][2];
#pragma unroll
  for (int mb = 0; mb < 2; ++mb)
#pragma unroll
    for (int nb = 0; nb < 2; ++nb) acc[mb][nb] = (floatx4){0.f,0.f,0.f,0.f};
  for (int k0 = 0; k0 < K; k0 += 64) {
#pragma unroll
    for (int p = 0; p < 2; ++p) {
      int idx = p*256 + tid;
      int row = idx >> 3, c8 = (idx & 7)*8;
      stage8(&Al[row*72 + c8], &Az[(size_t)(row0+row)*K + k0 + c8]);
      stage8(&Wl[row*72 + c8], &Wz[(size_t)(col0+row)*K + k0 + c8]);
    }
    __syncthreads();
    bf16x8 a0[2], a1[2], b0[2], b1[2];
#pragma unroll
    for (int mb = 0; mb < 2; ++mb) {
      a0[mb] = *(bf16x8*)&Al[(wr + mb*16 + lm)*72 + lq*8];
      a1[mb] = *(bf16x8*)&Al[(wr + mb*16 + lm)*72 + 32 + lq*8];
    }
#pragma unroll
    for (int nb = 0; nb < 2; ++nb) {
      b0[nb] = *(bf16x8*)&Wl[(wc + nb*16 + lm)*72 + lq*8];
      b1[nb] = *(bf16x8*)&Wl[(wc + nb*16 + lm)*72 + 32 + lq*8];
    }
#pragma unroll
    for (int mb = 0; mb < 2; ++mb)
#pragma unroll
      for (int nb = 0; nb < 2; ++nb) {
        acc[mb][nb] = MFMA16(a0[mb], b0[nb], acc[mb][nb]);
        acc[mb][nb] = MFMA16(a1[mb], b1[nb], acc[mb][nb]);
      }
    __syncthreads();
  }
  float lamv = 1.f;
  if (lam_ptr) lamv = softplusf(lam_ptr[0]) + 1e-6f;
#pragma unroll
  for (int mb = 0; mb < 2; ++mb) {
    float dsum[4] = {0.f,0.f,0.f,0.f};
#pragma unroll
    for (int nb = 0; nb < 2; ++nb) {
#pragma unroll
      for (int r = 0; r < 4; ++r) {
        int grow = row0 + wr + mb*16 + lq*4 + r;
        int gcol = col0 + wc + nb*16 + lm;
        float v = acc[mb][nb][r];
        if (rowdiv) v /= rowdiv[(size_t)z*KM + grow];
        if (Rz) {
          float rv = Rz[(size_t)grow*O + gcol];
          v += lamv * rv;
          dsum[r] += rv * v;
        }
        Cz[(size_t)grow*O + gcol] = (TO)v;
      }
    }
    if (dotout) {
#pragma unroll
      for (int r = 0; r < 4; ++r) {
        float s = dsum[r];
        s += __shfl_xor(s,1); s += __shfl_xor(s,2);
        s += __shfl_xor(s,4); s += __shfl_xor(s,8);
        if (lm == 0)
          atomicAdd(&dotout[(size_t)z*DD + row0 + wr + mb*16 + lq*4 + r], s);
      }
    }
  }
}

// ---------------- fp32 tile GEMM (head only, O=64) ----------------
__global__ __launch_bounds__(256) void gemm_f32_kernel(
    const float* __restrict__ A, int K,
    const float* __restrict__ W, const float* __restrict__ bias,
    float* __restrict__ C, int O)
{
  __shared__ float As[32][68];
  __shared__ float Ws[32][68];
  int t = threadIdx.x;
  int row0 = blockIdx.x * 64;
  int col0 = blockIdx.y * 64;
  int ti = t & 15, tj = t >> 4;
  float acc[4][4] = {};
  for (int k0 = 0; k0 < K; k0 += 32) {
#pragma unroll
    for (int p = 0; p < 2; ++p) {
      int idx = p*256 + t;
      int ar = idx >> 3, af = (idx & 7)*4;
      float4 av = *(const float4*)&A[(size_t)(row0+ar)*K + k0 + af];
      As[af+0][ar] = av.x; As[af+1][ar] = av.y;
      As[af+2][ar] = av.z; As[af+3][ar] = av.w;
      float4 wv = *(const float4*)&W[(size_t)(col0+ar)*K + k0 + af];
      Ws[af+0][ar] = wv.x; Ws[af+1][ar] = wv.y;
      Ws[af+2][ar] = wv.z; Ws[af+3][ar] = wv.w;
    }
    __syncthreads();
#pragma unroll
    for (int kk = 0; kk < 32; ++kk) {
      float4 a4 = *(float4*)&As[kk][ti*4];
      float4 b4 = *(float4*)&Ws[kk][tj*4];
      float a[4] = {a4.x, a4.y, a4.z, a4.w};
      float b[4] = {b4.x, b4.y, b4.z, b4.w};
#pragma unroll
      for (int x = 0; x < 4; ++x)
#pragma unroll
        for (int y = 0; y < 4; ++y) acc[x][y] += a[x]*b[y];
    }
    __syncthreads();
  }
#pragma unroll
  for (int x = 0; x < 4; ++x) {
    int r = row0 + ti*4 + x;
#pragma unroll
    for (int y = 0; y < 4; ++y) {
      int c = col0 + tj*4 + y;
      float v = fmaxf(acc[x][y] + bias[c], 0.f);
      C[(size_t)r*O + c] = v;
    }
  }
}

// ---------------- transpose-init: PT=RT=F^T, XT=0, RRA=rowdot ----------------
__global__ __launch_bounds__(256) void tinit_kernel(
    const float* __restrict__ F, float* __restrict__ PT, float* __restrict__ RT,
    float* __restrict__ XT, float* __restrict__ RRA)
{
  __shared__ float Ls[64][68];
  int t = threadIdx.x;
  int k0 = blockIdx.x*64, n0 = blockIdx.y*64, z = blockIdx.z;
#pragma unroll
  for (int p = 0; p < 4; ++p) {
    int idx = p*256 + t;
    int kr = idx >> 4, c4 = (idx & 15)*4;
    *(float4*)&Ls[kr][c4] = *(const float4*)&F[((size_t)z*KM + k0+kr)*DD + n0 + c4];
  }
  __syncthreads();
#pragma unroll
  for (int p = 0; p < 4; ++p) {
    int idx = p*256 + t;
    int nl = idx >> 4, k4 = (idx & 15)*4;
    float4 v = { Ls[k4+0][nl], Ls[k4+1][nl], Ls[k4+2][nl], Ls[k4+3][nl] };
    size_t o = ((size_t)z*DD + n0+nl)*KM + k0 + k4;
    *(float4*)&PT[o] = v;
    *(float4*)&RT[o] = v;
    float4 zr = {0.f,0.f,0.f,0.f};
    *(float4*)&XT[o] = zr;
    float s = v.x*v.x + v.y*v.y + v.z*v.z + v.w*v.w;
    s += __shfl_xor(s,1); s += __shfl_xor(s,2);
    s += __shfl_xor(s,4); s += __shfl_xor(s,8);
    if ((t & 15) == 0) atomicAdd(&RRA[z*DD + n0 + nl], s);
  }
}

// ---------------- merged CG update ----------------
__global__ __launch_bounds__(256) void cg_update_kernel(
    float* __restrict__ XT, float* __restrict__ RT,
    float* __restrict__ PT, const float* __restrict__ APT,
    float* __restrict__ RRA, float* __restrict__ PAP)
{
  __shared__ float red[256];
  int row = blockIdx.x;
  int t = threadIdx.x;
  float num = RRA[row], den = PAP[row];
  float alpha = (den > 1e-30f) ? num/den : 0.f;
  size_t base = (size_t)row*KM;
  float rl[4], pl[4];
  float s = 0.f;
#pragma unroll
  for (int u = 0; u < 4; ++u) {
    size_t i = base + u*256 + t;
    pl[u] = PT[i];
    float r = RT[i] - alpha*APT[i];
    XT[i] += alpha*pl[u];
    RT[i] = r;
    rl[u] = r;
    s += r*r;
  }
  red[t] = s; __syncthreads();
  for (int s2 = 128; s2 > 0; s2 >>= 1) { if (t < s2) red[t] += red[t+s2]; __syncthreads(); }
  float rrnew = red[0];
  float beta = (num > 1e-30f) ? rrnew/num : 0.f;
#pragma unroll
  for (int u = 0; u < 4; ++u) {
    size_t i = base + u*256 + t;
    PT[i] = rl[u] + beta*pl[u];
  }
  if (t == 0) { RRA[row] = rrnew; PAP[row] = 0.f; }
}

// ---------------- misc ----------------
__global__ __launch_bounds__(256) void zero_kernel(float* __restrict__ p, int n) {
  int idx = blockIdx.x*256 + threadIdx.x;
  if (idx < n) p[idx] = 0.f;
}
__global__ __launch_bounds__(256) void copy_kernel(
    float* __restrict__ dst, const float* __restrict__ src, int n)
{
  size_t idx = (size_t)blockIdx.x*256 + threadIdx.x;
  if (idx < (size_t)n) dst[idx] = src[idx];
}

// ---------------- RoPE (coalesced, de-interleaved QKV) ----------------
// QKV layout per row: [q 0..255 | k 256..511 | v 512..767]; pair rotation is
// in-thread. 0.125*log2e folded into Q. 2 rows per 256-thread block.
__global__ __launch_bounds__(256) void rope_split_kernel(
    const bf16* __restrict__ qkv, const float* __restrict__ enc0,
    const float* __restrict__ enc1, bf16* __restrict__ Qo,
    bf16* __restrict__ Ko)
{
  int t = threadIdx.x;
  int r = blockIdx.x*2 + (t >> 7);
  int c = (t & 127)*2;                    // even col
  int ts = r >> 10, i = r & 1023;
  int d = c & 63;
  const float* enc = (ts < BB) ? enc0 : enc1;
  int s = (ts < BB) ? ts : ts - BB;
  const float* eb = enc + (((size_t)s*2)*KM + i)*HD;
  float2 cs = *(const float2*)&eb[d];
  float2 sn = *(const float2*)&eb[(size_t)KM*HD + d];
  size_t base = (size_t)r*768;
  bf16x2 qv = *(const bf16x2*)&qkv[base + c];
  bf16x2 kv = *(const bf16x2*)&qkv[base + 256 + c];
  float q0 = (float)qv[0], q1 = (float)qv[1];
  float k0 = (float)kv[0], k1 = (float)kv[1];
  float oq0 = q0*cs.x - q1*sn.x, oq1 = q1*cs.y + q0*sn.y;
  float ok0 = k0*cs.x - k1*sn.x, ok1 = k1*cs.y + k0*sn.y;
  size_t o = (size_t)r*DD + c;
  bf16x2 qo = {(bf16)(0.1803368801f*oq0), (bf16)(0.1803368801f*oq1)};
  bf16x2 ko = {(bf16)ok0, (bf16)ok1};
  *(bf16x2*)&Qo[o] = qo;
  *(bf16x2*)&Ko[o] = ko;
}

// ---------------- V -> V^T transpose (per (stream,head)), strided src -------
// src row k of (ts,h): Vin[((size_t)ts*KM + k)*vstride + h*HD + d]
// out: VT[((ts*4+h)*HD + d)*KM + k]
__global__ __launch_bounds__(256) void vt_kernel(
    const bf16* __restrict__ Vin, int vstride, bf16* __restrict__ VT)
{
  __shared__ __align__(16) bf16 Ls[64*MS];
  int tid = threadIdx.x;
  int zh = blockIdx.x;
  int ts = zh >> 2, h = zh & 3;
  int k0 = blockIdx.y * 64;
#pragma unroll
  for (int p = 0; p < 2; ++p) {
    int idx = p*256 + tid;
    int kr = idx >> 3, c8 = (idx & 7)*8;
    *(uint4*)&Ls[kr*MS + c8] =
      *(const uint4*)&Vin[((size_t)ts*KM + k0 + kr)*vstride + h*HD + c8];
  }
  __syncthreads();
#pragma unroll
  for (int p = 0; p < 2; ++p) {
    int idx = p*256 + tid;
    int dr = idx >> 3, k8 = (idx & 7)*8;
    bf16 tmp[8] __attribute__((aligned(16)));
#pragma unroll
    for (int j = 0; j < 8; ++j) tmp[j] = Ls[(k8+j)*MS + dr];
    *(uint4*)&VT[((size_t)zh*HD + dr)*KM + k0 + k8] = *(uint4*)tmp;
  }
}

// ---------------- MFMA flash attention body (S^T scheme, V^T input) ----------
__device__ __forceinline__ void mha_body(
    const bf16* __restrict__ Qg, const bf16* __restrict__ Kg,
    const bf16* __restrict__ VTg, bf16* __restrict__ Og,
    size_t qkbase, size_t obase, size_t vbase, int qkstride,
    int q0, int tid, bf16* Qs, bf16* Ks, bf16* Vt)
{
  int lane = tid & 63, w = tid >> 6;
  int lm = lane & 15, lq = lane >> 4;
#pragma unroll
  for (int p = 0; p < 2; ++p) {
    int idx = p*256 + tid;
    int row = idx >> 3, c8 = (idx & 7)*8;
    *(uint4*)&Qs[row*MS + c8] =
      *(const uint4*)&Qg[qkbase + (size_t)(q0+row)*qkstride + c8];
  }
  __syncthreads();
  bf16x8 qa0 = *(bf16x8*)&Qs[(w*16 + lm)*MS + lq*8];
  bf16x8 qa1 = *(bf16x8*)&Qs[(w*16 + lm)*MS + 32 + lq*8];
  float m_ = -1e30f, l_ = 0.f;
  floatx4 oacc[4];
#pragma unroll
  for (int db = 0; db < 4; ++db) oacc[db] = (floatx4){0.f,0.f,0.f,0.f};

  for (int kt = 0; kt < KM; kt += 64) {
    __syncthreads();
#pragma unroll
    for (int p = 0; p < 2; ++p) {
      int idx = p*256 + tid;
      int row = idx >> 3, c8 = (idx & 7)*8;
      *(uint4*)&Ks[row*MS + c8] =
        *(const uint4*)&Kg[qkbase + (size_t)(kt+row)*qkstride + c8];
      *(uint4*)&Vt[row*MS + c8] =
        *(const uint4*)&VTg[vbase + (size_t)row*KM + kt + c8];
    }
    __syncthreads();
    floatx4 st[4];
#pragma unroll
    for (int kb = 0; kb < 4; ++kb) {
      bf16x8 a0 = *(bf16x8*)&Ks[(kb*16 + lm)*MS + lq*8];
      bf16x8 a1 = *(bf16x8*)&Ks[(kb*16 + lm)*MS + 32 + lq*8];
      floatx4 acc = (floatx4){0.f,0.f,0.f,0.f};
      acc = MFMA16(a0, qa0, acc);
      acc = MFMA16(a1, qa1, acc);
      st[kb] = acc;
    }
    float mx = -1e30f;
#pragma unroll
    for (int kb = 0; kb < 4; ++kb)
#pragma unroll
      for (int r = 0; r < 4; ++r) mx = fmaxf(mx, st[kb][r]);
    mx = fmaxf(mx, __shfl_xor(mx, 16));
    mx = fmaxf(mx, __shfl_xor(mx, 32));
    if (__ballot(mx > m_)) {
      float mn = fmaxf(m_, mx);
      float al = exp2f(m_ - mn);
      m_ = mn;
      l_ *= al;
#pragma unroll
      for (int db = 0; db < 4; ++db) {
        oacc[db][0] *= al; oacc[db][1] *= al;
        oacc[db][2] *= al; oacc[db][3] *= al;
      }
    }
    float ssum = 0.f;
#pragma unroll
    for (int kb = 0; kb < 4; ++kb)
#pragma unroll
      for (int r = 0; r < 4; ++r) {
        float p = exp2f(st[kb][r] - m_);
        st[kb][r] = p;
        ssum += p;
      }
    ssum += __shfl_xor(ssum, 16);
    ssum += __shfl_xor(ssum, 32);
    l_ += ssum;
#pragma unroll
    for (int kb = 0; kb < 4; ++kb) {
      short4v pb = pack4(st[kb][0], st[kb][1], st[kb][2], st[kb][3]);
#pragma unroll
      for (int db = 0; db < 4; ++db) {
        short4v va = *(const short4v*)&Vt[(db*16 + lm)*MS + kb*16 + lq*4];
        oacc[db] = MFMA1K(va, pb, oacc[db]);
      }
    }
  }
  float inv = 1.f / l_;
  int q = q0 + w*16 + lm;
#pragma unroll
  for (int db = 0; db < 4; ++db) {
    bf16x4 o4 = { (bf16)(oacc[db][0]*inv), (bf16)(oacc[db][1]*inv),
                  (bf16)(oacc[db][2]*inv), (bf16)(oacc[db][3]*inv) };
    *(bf16x4*)&Og[obase + (size_t)q*DD + db*16 + lq*4] = o4;
  }
}

// self attention: grid (zh=64, qtile=16); Q/K row stride 256
__global__ __launch_bounds__(256) void mha_kernel(
    const bf16* __restrict__ Qg, const bf16* __restrict__ Kg,
    const bf16* __restrict__ VTg, bf16* __restrict__ Og)
{
  __shared__ __align__(16) bf16 Qs[64*MS];
  __shared__ __align__(16) bf16 Ks[64*MS];
  __shared__ __align__(16) bf16 Vt[64*MS];
  int zh = blockIdx.x;
  int z = zh >> 2, h = zh & 3;
  size_t base = ((size_t)z*KM)*DD + (size_t)h*HD;
  size_t vbase = (size_t)zh*HD*KM;
  mha_body(Qg, Kg, VTg, Og, base, base, vbase, DD,
           blockIdx.y*64, threadIdx.x, Qs, Ks, Vt);
}

// cross attention, both directions: grid (zh=32, qtile=16, dir=2)
// Q/K live in QKV2 (row stride 512, q at col 0, k at.. same buffer other half)
__global__ __launch_bounds__(256) void mha_cross_kernel(
    const bf16* __restrict__ QKV2, const bf16* __restrict__ VT2,
    bf16* __restrict__ ATTO2)
{
  __shared__ __align__(16) bf16 Qs[64*MS];
  __shared__ __align__(16) bf16 Ks[64*MS];
  __shared__ __align__(16) bf16 Vt[64*MS];
  int dir = blockIdx.z;
  const bf16* Qg  = QKV2 + (dir ? (size_t)BN*512 : 0);
  const bf16* Kg  = QKV2 + (dir ? 0 : (size_t)BN*512);
  const bf16* VTg = VT2  + (dir ? 0 : (size_t)32*HD*KM);
  bf16*       Og  = ATTO2 + (dir ? (size_t)BN*DD : 0);
  int zh = blockIdx.x;
  int z = zh >> 2, h = zh & 3;
  size_t qkbase = ((size_t)z*KM)*512 + (size_t)h*HD;
  size_t obase  = ((size_t)z*KM)*DD  + (size_t)h*HD;
  size_t vbase  = (size_t)zh*HD*KM;
  mha_body(Qg, Kg, VTg, Og, qkbase, obase, vbase, 512,
           blockIdx.y*64, threadIdx.x, Qs, Ks, Vt);
}

// ---------------- in-place LayerNorm + exact GELU (bf16, width 512) --------
__global__ __launch_bounds__(256) void ln_gelu_kernel(
    bf16* __restrict__ Hb, const float* __restrict__ g,
    const float* __restrict__ be)
{
  __shared__ float red[256];
  int r = blockIdx.x, t = threadIdx.x;
  bf16x2 hv = *(bf16x2*)&Hb[(size_t)r*512 + 2*t];
  float x0 = (float)hv[0], x1 = (float)hv[1];
  red[t] = x0 + x1; __syncthreads();
  for (int s2 = 128; s2 > 0; s2 >>= 1) { if (t < s2) red[t] += red[t+s2]; __syncthreads(); }
  float mu = red[0] * (1.f/512.f); __syncthreads();
  float d0 = x0 - mu, d1 = x1 - mu;
  red[t] = d0*d0 + d1*d1; __syncthreads();
  for (int s2 = 128; s2 > 0; s2 >>= 1) { if (t < s2) red[t] += red[t+s2]; __syncthreads(); }
  float rstd = rsqrtf(red[0]*(1.f/512.f) + 1e-5f);
  float2 gv = *(const float2*)&g[2*t];
  float2 bv = *(const float2*)&be[2*t];
  float h0 = d0*rstd*gv.x + bv.x;
  float h1 = d1*rstd*gv.y + bv.y;
  h0 = 0.5f*h0*(1.f + erff(h0*0.70710678118f));
  h1 = 0.5f*h1*(1.f + erff(h1*0.70710678118f));
  bf16x2 ov = { (bf16)h0, (bf16)h1 };
  *(bf16x2*)&Hb[(size_t)r*512 + 2*t] = ov;
}

// ---------------- final head 2 ----------------
__global__ __launch_bounds__(256) void head2_kernel(
    const float* __restrict__ Hb, const float* __restrict__ w,
    const float* __restrict__ b, float* __restrict__ out)
{
  int r = blockIdx.x*256 + threadIdx.x;
  float acc = b[0];
#pragma unroll
  for (int k = 0; k < 64; ++k) acc += Hb[(size_t)r*64 + k]*w[k];
  out[r] = 1.f/(1.f + expf(-acc));
}

extern "C" void kernel_launch(void* const* d_in, const int* in_sizes, int n_in,
                              void* d_out, int out_size, void* d_ws, size_t ws_size,
                              hipStream_t stream)
{
  (void)in_sizes; (void)n_in; (void)out_size; (void)ws_size;
  const float* fa      = (const float*)d_in[0];
  const float* fb      = (const float*)d_in[1];
  const int*   matches = (const int*)d_in[2];
  const float* ka      = (const float*)d_in[3];
  const float* kb      = (const float*)d_in[4];
  const float* lam     = (const float*)d_in[5];
  const float* beta    = (const float*)d_in[6];
  const float* Wr      = (const float*)d_in[7];
  const float* pW1     = (const float*)d_in[8];
  const float* pb1     = (const float*)d_in[9];
  const float* pW2     = (const float*)d_in[10];
  const float* pb2     = (const float*)d_in[11];
  const float* sWqkv   = (const float*)d_in[12];
  const float* sbqkv   = (const float*)d_in[13];
  const float* sWo     = (const float*)d_in[14];
  const float* sbo     = (const float*)d_in[15];
  const float* sW1     = (const float*)d_in[16];
  const float* sb1     = (const float*)d_in[17];
  const float* sg      = (const float*)d_in[18];
  const float* sbe     = (const float*)d_in[19];
  const float* sW2     = (const float*)d_in[20];
  const float* sb2     = (const float*)d_in[21];
  const float* cWqk    = (const float*)d_in[22];
  const float* cbqk    = (const float*)d_in[23];
  const float* cWv     = (const float*)d_in[24];
  const float* cbv     = (const float*)d_in[25];
  const float* cWo     = (const float*)d_in[26];
  const float* cbo     = (const float*)d_in[27];
  const float* cW1     = (const float*)d_in[28];
  const float* cb1     = (const float*)d_in[29];
  const float* cgw     = (const float*)d_in[30];
  const float* cbe     = (const float*)d_in[31];
  const float* cW2     = (const float*)d_in[32];
  const float* cb2     = (const float*)d_in[33];

  char* wsb = (char*)d_ws;
  float* DCAT = (float*)wsb;                      // 16,777,216 B
  float* ENC0 = (float*)(wsb + 16777216);
  float* ENC1 = (float*)(wsb + 20971520);
  float* XY0  = (float*)(wsb + 25165824);
  float* XY1  = (float*)(wsb + 25231360);
  float* ROWS = (float*)(wsb + 25296896);
  float* RRA  = (float*)(wsb + 25329664);
  float* PAP  = (float*)(wsb + 25346048);
  char*  POOL = wsb + 25354240;
  const size_t SLOT = 8388608;
  // CG phase
  bf16*  KMATH = (bf16*)POOL;                    // slots 0-1
  float* FBUF  = (float*)(POOL + 2*SLOT);
  float* PT    = (float*)(POOL + 3*SLOT);
  float* RT    = (float*)(POOL + 4*SLOT);
  float* XT    = (float*)(POOL + 5*SLOT);
  float* APT   = (float*)(POOL + 6*SLOT);
  // transformer phase
  bf16*  QKV   = (bf16*)POOL;                    // slots 0-2 (q|k|v cols)
  bf16*  QR    = (bf16*)(POOL + 3*SLOT);
  bf16*  KR    = (bf16*)(POOL + 4*SLOT);
  bf16*  VTG   = (bf16*)(POOL + 8*SLOT);         // slot 8 (V^T, self)
  bf16*  ATTO  = (bf16*)POOL;                    // slot 0
  bf16*  MSG   = (bf16*)(POOL + 1*SLOT);
  bf16*  H1    = (bf16*)(POOL + 6*SLOT);         // slots 6-7
  bf16*  QKV2  = (bf16*)POOL;                    // slots 0-1 (cross q|v cols)
  bf16*  ATTO2 = (bf16*)(POOL + 2*SLOT);
  bf16*  MSG2  = (bf16*)(POOL + 3*SLOT);
  bf16*  VT2   = (bf16*)(POOL + 4*SLOT);         // slot 4 (V^T, cross)
  bf16*  H1C   = H1;
  float* HBUF  = (float*)POOL;

  const float scq = 0.42466090f;   // 64^-0.25 * sqrt(log2 e)

  // ---- gather / posenc / Kmat ----
  gather_kernel<<<BN, 256, 0, stream>>>(fa, fb, matches, ka, kb, FBUF, XY0, XY1);
  posenc_kernel<<<BN, 64, 0, stream>>>(XY0, Wr, ENC0);
  posenc_kernel<<<BN, 64, 0, stream>>>(XY1, Wr, ENC1);
  kmat_kernel<<<BN, 256, 0, stream>>>(XY0, beta, KMATH, ROWS);

  // ---- CG (transposed state) ----
  zero_kernel<<<24, 256, 0, stream>>>(RRA, 6144);
  tinit_kernel<<<dim3(16,4,BB), 256, 0, stream>>>(FBUF, PT, RT, XT, RRA);
  for (int it = 0; it < CG_ITERS; ++it) {
    mv64_kernel<float,bf16,float><<<dim3(4,16,BB), 256, 0, stream>>>(
        PT, 1024, KMATH, APT, 1024, PT, lam, (const float*)0, PAP,
        262144, 1048576, 262144, 262144);
    cg_update_kernel<<<2048, 256, 0, stream>>>(XT, RT, PT, APT, RRA, PAP);
  }

  // ---- d0 = f_i ; d1 = rownorm(Kmat) @ C ----
  copy_kernel<<<8192, 256, 0, stream>>>(DCAT, FBUF, BN*DD);
  mv64_kernel<bf16,float,float><<<dim3(16,4,BB), 256, 0, stream>>>(
      KMATH, 1024, XT, DCAT + (size_t)BN*DD, 256,
      (const float*)0, (const float*)0, ROWS, (float*)0,
      1048576, 262144, 262144, 0);

  // ---- transformer layers ----
  for (int l = 0; l < NLAYER; ++l) {
    // self block
    mm_kernel<128,1,0,float,float,float,bf16><<<dim3(128,6,1), 256, 0, stream>>>(
        DCAT, (const float*)0, 256, 256, sWqkv + (size_t)l*768*256, sbqkv + l*768,
        (const float*)0, (const float*)0, QKV, 768, 1.f, 1.f, (const float*)0);
    rope_split_kernel<<<8192, 256, 0, stream>>>(QKV, ENC0, ENC1, QR, KR);
    vt_kernel<<<dim3(64,16), 256, 0, stream>>>(QKV + 512, 768, VTG);
    mha_kernel<<<dim3(64,16), 256, 0, stream>>>(QR, KR, VTG, ATTO);
    mm_kernel<64,0,0,bf16,bf16,float,bf16><<<dim3(128,4,1), 256, 0, stream>>>(
        ATTO, (const bf16*)0, 256, 256, sWo + (size_t)l*256*256, sbo + l*256,
        (const float*)0, (const float*)0, MSG, 256, 1.f, 1.f, (const float*)0);
    mm_kernel<128,0,0,float,bf16,float,bf16><<<dim3(128,4,1), 256, 0, stream>>>(
        DCAT, MSG, 256, 512, sW1 + (size_t)l*512*512, sb1 + l*512,
        (const float*)0, (const float*)0, H1, 512, 1.f, 1.f, (const float*)0);
    ln_gelu_kernel<<<N2, 256, 0, stream>>>(H1, sg + l*512, sbe + l*512);
    mm_kernel<64,0,0,bf16,bf16,float,float><<<dim3(128,4,1), 256, 0, stream>>>(
        H1, (const bf16*)0, 512, 512, sW2 + (size_t)l*256*512, sb2 + l*256,
        (const float*)0, (const float*)0, DCAT, 256, 1.f, 1.f, DCAT);
    // cross block: fused qk|v projection into QKV2 (row stride 512)
    mm_kernel<128,0,1,float,float,float,bf16><<<dim3(128,4,1), 256, 0, stream>>>(
        DCAT, (const float*)0, 256, 256, cWqk + (size_t)l*256*256, cbqk + l*256,
        cWv + (size_t)l*256*256, cbv + l*256, QKV2, 512, scq, 1.f,
        (const float*)0);
    vt_kernel<<<dim3(64,16), 256, 0, stream>>>(QKV2 + 256, 512, VT2);
    mha_cross_kernel<<<dim3(32,16,2), 256, 0, stream>>>(QKV2, VT2, ATTO2);
    mm_kernel<64,0,0,bf16,bf16,float,bf16><<<dim3(128,4,1), 256, 0, stream>>>(
        ATTO2, (const bf16*)0, 256, 256, cWo + (size_t)l*256*256, cbo + l*256,
        (const float*)0, (const float*)0, MSG2, 256, 1.f, 1.f, (const float*)0);
    mm_kernel<128,0,0,float,bf16,float,bf16><<<dim3(128,4,1), 256, 0, stream>>>(
        DCAT, MSG2, 256, 512, cW1 + (size_t)l*512*512, cb1 + l*512,
        (const float*)0, (const float*)0, H1C, 512, 1.f, 1.f, (const float*)0);
    ln_gelu_kernel<<<N2, 256, 0, stream>>>(H1C, cgw + l*512, cbe + l*512);
    mm_kernel<64,0,0,bf16,bf16,float,float><<<dim3(128,4,1), 256, 0, stream>>>(
        H1C, (const bf16*)0, 512, 512, cW2 + (size_t)l*256*512, cb2 + l*256,
        (const float*)0, (const float*)0, DCAT, 256, 1.f, 1.f, DCAT);
  }

  // ---- head ----
  gemm_f32_kernel<<<dim3(128,1), 256, 0, stream>>>(DCAT, 256, pW1, pb1, HBUF, 64);
  head2_kernel<<<32, 256, 0, stream>>>(HBUF, pW2, pb2, (float*)d_out);
}

// Round 10
// 1123.398 us; speedup vs baseline: 1.1844x; 1.1844x over previous
//
#include <hip/hip_runtime.h>
#include <math.h>

// Problem constants
#define BB 8
#define MM 2048
#define KM 1024
#define DD 256
#define HH 4
#define HD 64
#define NLAYER 2
#define BN (BB*KM)        // 8192 rows per "decoder half"
#define N2 (2*BN)         // 16384 rows d0||d1
#define CG_ITERS 6

// XOR-swizzled LDS addressing for the attention tiles: stride 64 (no pad),
// 16-byte blocks permuted by row. Conflict-free for uint4 stores, bf16x8
// reads, and short4v reads — and keeps every access 16B/8B aligned.
#define SWZ(r,c) (((r)<<6) + ((((c)>>3) ^ ((r)&7))<<3) + ((c)&7))

typedef __bf16 bf16;
typedef __bf16 bf16x8 __attribute__((ext_vector_type(8)));
typedef __bf16 bf16x4 __attribute__((ext_vector_type(4)));
typedef __bf16 bf16x2 __attribute__((ext_vector_type(2)));
typedef short  short4v __attribute__((ext_vector_type(4)));
typedef float  floatx4 __attribute__((ext_vector_type(4)));
#define MFMA16(a,b,c) __builtin_amdgcn_mfma_f32_16x16x32_bf16(a,b,c,0,0,0)

// K=16 bf16 MFMA (PV stage: S^T C-frag == its B-operand layout).
#if defined(__HIP_DEVICE_COMPILE__)
  #if __has_builtin(__builtin_amdgcn_mfma_f32_16x16x16bf16_1k)
    #define MFMA1K(a,b,c) __builtin_amdgcn_mfma_f32_16x16x16bf16_1k(a,b,c,0,0,0)
  #else
    #error "device pass lacks mfma_f32_16x16x16bf16_1k"
  #endif
#else
  #define MFMA1K(a,b,c) (c)   /* host stub, never executed */
#endif

__device__ __forceinline__ float softplusf(float x) {
  return fmaxf(x, 0.f) + log1pf(expf(-fabsf(x)));
}

__device__ __forceinline__ short4v pack4(float a, float b, float c, float d) {
  bf16x4 v = {(bf16)a,(bf16)b,(bf16)c,(bf16)d};
  short4v s;
  __builtin_memcpy(&s, &v, 8);
  return s;
}

// stage 8 elements (convert to bf16 if needed), 16B LDS store
__device__ __forceinline__ void stage8(bf16* dst, const float* src) {
  float4 a = *(const float4*)src;
  float4 b = *(const float4*)(src + 4);
  bf16x8 v = { (bf16)a.x,(bf16)a.y,(bf16)a.z,(bf16)a.w,
               (bf16)b.x,(bf16)b.y,(bf16)b.z,(bf16)b.w };
  *(bf16x8*)dst = v;
}
__device__ __forceinline__ void stage8(bf16* dst, const bf16* src) {
  *(uint4*)dst = *(const uint4*)src;
}

// ---------------- gather ----------------
__global__ __launch_bounds__(256) void gather_kernel(
    const float* __restrict__ fa, const float* __restrict__ fb,
    const int* __restrict__ matches, const float* __restrict__ ka,
    const float* __restrict__ kb, float* __restrict__ F,
    float* __restrict__ xy0, float* __restrict__ xy1)
{
  int si = blockIdx.x;
  int s  = si >> 10;
  int t  = threadIdx.x;
  int ia = matches[(size_t)si*2+0];
  int ib = matches[(size_t)si*2+1];
  F[(size_t)si*DD + t] = fb[((size_t)s*MM + ib)*DD + t]
                       - fa[((size_t)s*MM + ia)*DD + t];
  if (t == 0) {
    xy0[(size_t)si*2+0] = ka[((size_t)s*MM + ia)*2+0];
    xy0[(size_t)si*2+1] = ka[((size_t)s*MM + ia)*2+1];
    xy1[(size_t)si*2+0] = kb[((size_t)s*MM + ib)*2+0];
    xy1[(size_t)si*2+1] = kb[((size_t)s*MM + ib)*2+1];
  }
}

// ---------------- positional encoding ----------------
__global__ __launch_bounds__(64) void posenc_kernel(
    const float* __restrict__ xy, const float* __restrict__ Wr,
    float* __restrict__ enc)
{
  int si = blockIdx.x; int s = si >> 10, i = si & 1023;
  int d = threadIdx.x; int p = d >> 1;
  float x = xy[(size_t)si*2], y = xy[(size_t)si*2+1];
  float pr = Wr[p*2]*x + Wr[p*2+1]*y;
  enc[(((size_t)s*2+0)*KM + i)*HD + d] = cosf(pr);
  enc[(((size_t)s*2+1)*KM + i)*HD + d] = sinf(pr);
}

// ---------------- Kmat (bf16) + rowsum ----------------
__global__ __launch_bounds__(256) void kmat_kernel(
    const float* __restrict__ xy0, const float* __restrict__ beta_ptr,
    bf16* __restrict__ Km, float* __restrict__ rowsum)
{
  __shared__ float red[256];
  int si = blockIdx.x; int s = si >> 10;
  int t = threadIdx.x;
  float beta_r = softplusf(beta_ptr[0]);
  float xi = xy0[(size_t)si*2], yi = xy0[(size_t)si*2+1];
  const float* xys = xy0 + (size_t)s*KM*2;
  float sum = 0.f;
  for (int jj = 0; jj < 4; ++jj) {
    int j = jj*256 + t;
    float dx = xi - xys[j*2], dy = yi - xys[j*2+1];
    float v = expf(-beta_r*(dx*dx + dy*dy));
    bf16 vb = (bf16)v;
    Km[(size_t)si*KM + j] = vb;
    sum += (float)vb;
  }
  red[t] = sum; __syncthreads();
  for (int s2 = 128; s2 > 0; s2 >>= 1) { if (t < s2) red[t] += red[t+s2]; __syncthreads(); }
  if (t == 0) rowsum[si] = red[0] + 1e-6f;
}

// ---------------- MFMA GEMM, tile 128xNT (NT=128 or 64), BK=64 ----------------
// C = [A1|A2] @ Wsel.T, epilogue (v+bias)*scale (+resid).
// WPERM: W row index perm(j)=(j&255)*3+(j>>8)  (qkv channel de-interleave)
// DUALW: cols [0,256) from W/bias/scale, cols [256,512) from Wb/biasb/scaleb
template<int NT, int WPERM, int DUALW,
         typename TA1, typename TA2, typename TW, typename TO>
__global__ __launch_bounds__(256) void mm_kernel(
    const TA1* __restrict__ A1, const TA2* __restrict__ A2, int K1, int K,
    const TW* __restrict__ W, const float* __restrict__ bias,
    const TW* __restrict__ Wb, const float* __restrict__ biasb,
    TO* __restrict__ C, int O, float scale, float scaleb,
    const float* __restrict__ resid)
{
  __shared__ __align__(16) bf16 Al[128*72];
  __shared__ __align__(16) bf16 Wl[NT*72];
  constexpr int MB = (NT == 128) ? 4 : 2;
  int tid = threadIdx.x;
  int row0 = blockIdx.x*128, col0 = blockIdx.y*NT;
  int lane = tid & 63, w = tid >> 6;
  int wr = (NT == 128) ? (w>>1)*64 : w*32;
  int wc = (NT == 128) ? (w&1)*64 : 0;
  int lm = lane & 15, lq = lane >> 4;
  floatx4 acc[MB][4];
#pragma unroll
  for (int mb = 0; mb < MB; ++mb)
#pragma unroll
    for (int nb = 0; nb < 4; ++nb) acc[mb][nb] = (floatx4){0.f,0.f,0.f,0.f};
  for (int k0 = 0; k0 < K; k0 += 64) {
#pragma unroll
    for (int p = 0; p < 4; ++p) {
      int idx = p*256 + tid;
      int row = idx >> 3, c8 = (idx & 7)*8;
      if (k0 < K1) stage8(&Al[row*72 + c8], &A1[(size_t)(row0+row)*K1 + k0 + c8]);
      else         stage8(&Al[row*72 + c8], &A2[(size_t)(row0+row)*(K-K1) + (k0-K1) + c8]);
    }
#pragma unroll
    for (int p = 0; p < NT/32; ++p) {
      int idx = p*256 + tid;
      int row = idx >> 3, c8 = (idx & 7)*8;
      int wg = col0 + row;
      const TW* wsrc; int wrow;
      if (DUALW && wg >= 256) { wsrc = Wb; wrow = wg - 256; }
      else { wsrc = W; wrow = WPERM ? ((wg & 255)*3 + (wg >> 8)) : wg; }
      stage8(&Wl[row*72 + c8], &wsrc[(size_t)wrow*K + k0 + c8]);
    }
    __syncthreads();
    bf16x8 af[MB][2], bfr[4][2];
#pragma unroll
    for (int mb = 0; mb < MB; ++mb) {
      af[mb][0] = *(bf16x8*)&Al[(wr + mb*16 + lm)*72 + lq*8];
      af[mb][1] = *(bf16x8*)&Al[(wr + mb*16 + lm)*72 + 32 + lq*8];
    }
#pragma unroll
    for (int nb = 0; nb < 4; ++nb) {
      bfr[nb][0] = *(bf16x8*)&Wl[(wc + nb*16 + lm)*72 + lq*8];
      bfr[nb][1] = *(bf16x8*)&Wl[(wc + nb*16 + lm)*72 + 32 + lq*8];
    }
#pragma unroll
    for (int mb = 0; mb < MB; ++mb)
#pragma unroll
      for (int nb = 0; nb < 4; ++nb) {
        acc[mb][nb] = MFMA16(af[mb][0], bfr[nb][0], acc[mb][nb]);
        acc[mb][nb] = MFMA16(af[mb][1], bfr[nb][1], acc[mb][nb]);
      }
    __syncthreads();
  }
#pragma unroll
  for (int mb = 0; mb < MB; ++mb) {
#pragma unroll
    for (int nb = 0; nb < 4; ++nb) {
#pragma unroll
      for (int r = 0; r < 4; ++r) {
        int grow = row0 + wr + mb*16 + lq*4 + r;
        int gcol = col0 + wc + nb*16 + lm;
        float v = acc[mb][nb][r];
        float bv = 0.f, scl = scale;
        if (DUALW && gcol >= 256) {
          if (biasb) bv = biasb[gcol - 256];
          scl = scaleb;
        } else if (bias) {
          bv = bias[WPERM ? ((gcol & 255)*3 + (gcol >> 8)) : gcol];
        }
        v = (v + bv) * scl;
        if (resid) v += resid[(size_t)grow*O + gcol];
        C[(size_t)grow*O + gcol] = (TO)v;
      }
    }
  }
}

// ---------------- MFMA matvec-GEMM, 64x64 tile, BK=64, batched over z --------
template<typename TA, typename TW, typename TO>
__global__ __launch_bounds__(256) void mv64_kernel(
    const TA* __restrict__ A, int K, const TW* __restrict__ W,
    TO* __restrict__ C, int O,
    const float* __restrict__ resid, const float* __restrict__ lam_ptr,
    const float* __restrict__ rowdiv, float* __restrict__ dotout,
    long zsA, long zsW, long zsC, long zsR)
{
  __shared__ __align__(16) bf16 Al[64*72];
  __shared__ __align__(16) bf16 Wl[64*72];
  int tid = threadIdx.x;
  int z = blockIdx.z;
  const TA* Az = A + (size_t)z*zsA;
  const TW* Wz = W + (size_t)z*zsW;
  TO* Cz = C + (size_t)z*zsC;
  const float* Rz = resid ? (resid + (size_t)z*zsR) : (const float*)0;
  int row0 = blockIdx.x*64, col0 = blockIdx.y*64;
  int lane = tid & 63, w = tid >> 6;
  int wr = (w>>1)*32, wc = (w&1)*32;
  int lm = lane & 15, lq = lane >> 4;
  floatx4 acc[2][2];
#pragma unroll
  for (int mb = 0; mb < 2; ++mb)
#pragma unroll
    for (int nb = 0; nb < 2; ++nb) acc[mb][nb] = (floatx4){0.f,0.f,0.f,0.f};
  for (int k0 = 0; k0 < K; k0 += 64) {
#pragma unroll
    for (int p = 0; p < 2; ++p) {
      int idx = p*256 + tid;
      int row = idx >> 3, c8 = (idx & 7)*8;
      stage8(&Al[row*72 + c8], &Az[(size_t)(row0+row)*K + k0 + c8]);
      stage8(&Wl[row*72 + c8], &Wz[(size_t)(col0+row)*K + k0 + c8]);
    }
    __syncthreads();
    bf16x8 a0[2], a1[2], b0[2], b1[2];
#pragma unroll
    for (int mb = 0; mb < 2; ++mb) {
      a0[mb] = *(bf16x8*)&Al[(wr + mb*16 + lm)*72 + lq*8];
      a1[mb] = *(bf16x8*)&Al[(wr + mb*16 + lm)*72 + 32 + lq*8];
    }
#pragma unroll
    for (int nb = 0; nb < 2; ++nb) {
      b0[nb] = *(bf16x8*)&Wl[(wc + nb*16 + lm)*72 + lq*8];
      b1[nb] = *(bf16x8*)&Wl[(wc + nb*16 + lm)*72 + 32 + lq*8];
    }
#pragma unroll
    for (int mb = 0; mb < 2; ++mb)
#pragma unroll
      for (int nb = 0; nb < 2; ++nb) {
        acc[mb][nb] = MFMA16(a0[mb], b0[nb], acc[mb][nb]);
        acc[mb][nb] = MFMA16(a1[mb], b1[nb], acc[mb][nb]);
      }
    __syncthreads();
  }
  float lamv = 1.f;
  if (lam_ptr) lamv = softplusf(lam_ptr[0]) + 1e-6f;
#pragma unroll
  for (int mb = 0; mb < 2; ++mb) {
    float dsum[4] = {0.f,0.f,0.f,0.f};
#pragma unroll
    for (int nb = 0; nb < 2; ++nb) {
#pragma unroll
      for (int r = 0; r < 4; ++r) {
        int grow = row0 + wr + mb*16 + lq*4 + r;
        int gcol = col0 + wc + nb*16 + lm;
        float v = acc[mb][nb][r];
        if (rowdiv) v /= rowdiv[(size_t)z*KM + grow];
        if (Rz) {
          float rv = Rz[(size_t)grow*O + gcol];
          v += lamv * rv;
          dsum[r] += rv * v;
        }
        Cz[(size_t)grow*O + gcol] = (TO)v;
      }
    }
    if (dotout) {
#pragma unroll
      for (int r = 0; r < 4; ++r) {
        float s = dsum[r];
        s += __shfl_xor(s,1); s += __shfl_xor(s,2);
        s += __shfl_xor(s,4); s += __shfl_xor(s,8);
        if (lm == 0)
          atomicAdd(&dotout[(size_t)z*DD + row0 + wr + mb*16 + lq*4 + r], s);
      }
    }
  }
}

// ---------------- fp32 tile GEMM (head only, O=64) ----------------
__global__ __launch_bounds__(256) void gemm_f32_kernel(
    const float* __restrict__ A, int K,
    const float* __restrict__ W, const float* __restrict__ bias,
    float* __restrict__ C, int O)
{
  __shared__ float As[32][68];
  __shared__ float Ws[32][68];
  int t = threadIdx.x;
  int row0 = blockIdx.x * 64;
  int col0 = blockIdx.y * 64;
  int ti = t & 15, tj = t >> 4;
  float acc[4][4] = {};
  for (int k0 = 0; k0 < K; k0 += 32) {
#pragma unroll
    for (int p = 0; p < 2; ++p) {
      int idx = p*256 + t;
      int ar = idx >> 3, af = (idx & 7)*4;
      float4 av = *(const float4*)&A[(size_t)(row0+ar)*K + k0 + af];
      As[af+0][ar] = av.x; As[af+1][ar] = av.y;
      As[af+2][ar] = av.z; As[af+3][ar] = av.w;
      float4 wv = *(const float4*)&W[(size_t)(col0+ar)*K + k0 + af];
      Ws[af+0][ar] = wv.x; Ws[af+1][ar] = wv.y;
      Ws[af+2][ar] = wv.z; Ws[af+3][ar] = wv.w;
    }
    __syncthreads();
#pragma unroll
    for (int kk = 0; kk < 32; ++kk) {
      float4 a4 = *(float4*)&As[kk][ti*4];
      float4 b4 = *(float4*)&Ws[kk][tj*4];
      float a[4] = {a4.x, a4.y, a4.z, a4.w};
      float b[4] = {b4.x, b4.y, b4.z, b4.w};
#pragma unroll
      for (int x = 0; x < 4; ++x)
#pragma unroll
        for (int y = 0; y < 4; ++y) acc[x][y] += a[x]*b[y];
    }
    __syncthreads();
  }
#pragma unroll
  for (int x = 0; x < 4; ++x) {
    int r = row0 + ti*4 + x;
#pragma unroll
    for (int y = 0; y < 4; ++y) {
      int c = col0 + tj*4 + y;
      float v = fmaxf(acc[x][y] + bias[c], 0.f);
      C[(size_t)r*O + c] = v;
    }
  }
}

// ---------------- transpose-init: PT=RT=F^T, XT=0, RRA=rowdot ----------------
__global__ __launch_bounds__(256) void tinit_kernel(
    const float* __restrict__ F, float* __restrict__ PT, float* __restrict__ RT,
    float* __restrict__ XT, float* __restrict__ RRA)
{
  __shared__ float Ls[64][68];
  int t = threadIdx.x;
  int k0 = blockIdx.x*64, n0 = blockIdx.y*64, z = blockIdx.z;
#pragma unroll
  for (int p = 0; p < 4; ++p) {
    int idx = p*256 + t;
    int kr = idx >> 4, c4 = (idx & 15)*4;
    *(float4*)&Ls[kr][c4] = *(const float4*)&F[((size_t)z*KM + k0+kr)*DD + n0 + c4];
  }
  __syncthreads();
#pragma unroll
  for (int p = 0; p < 4; ++p) {
    int idx = p*256 + t;
    int nl = idx >> 4, k4 = (idx & 15)*4;
    float4 v = { Ls[k4+0][nl], Ls[k4+1][nl], Ls[k4+2][nl], Ls[k4+3][nl] };
    size_t o = ((size_t)z*DD + n0+nl)*KM + k0 + k4;
    *(float4*)&PT[o] = v;
    *(float4*)&RT[o] = v;
    float4 zr = {0.f,0.f,0.f,0.f};
    *(float4*)&XT[o] = zr;
    float s = v.x*v.x + v.y*v.y + v.z*v.z + v.w*v.w;
    s += __shfl_xor(s,1); s += __shfl_xor(s,2);
    s += __shfl_xor(s,4); s += __shfl_xor(s,8);
    if ((t & 15) == 0) atomicAdd(&RRA[z*DD + n0 + nl], s);
  }
}

// ---------------- merged CG update ----------------
__global__ __launch_bounds__(256) void cg_update_kernel(
    float* __restrict__ XT, float* __restrict__ RT,
    float* __restrict__ PT, const float* __restrict__ APT,
    float* __restrict__ RRA, float* __restrict__ PAP)
{
  __shared__ float red[256];
  int row = blockIdx.x;
  int t = threadIdx.x;
  float num = RRA[row], den = PAP[row];
  float alpha = (den > 1e-30f) ? num/den : 0.f;
  size_t base = (size_t)row*KM;
  float rl[4], pl[4];
  float s = 0.f;
#pragma unroll
  for (int u = 0; u < 4; ++u) {
    size_t i = base + u*256 + t;
    pl[u] = PT[i];
    float r = RT[i] - alpha*APT[i];
    XT[i] += alpha*pl[u];
    RT[i] = r;
    rl[u] = r;
    s += r*r;
  }
  red[t] = s; __syncthreads();
  for (int s2 = 128; s2 > 0; s2 >>= 1) { if (t < s2) red[t] += red[t+s2]; __syncthreads(); }
  float rrnew = red[0];
  float beta = (num > 1e-30f) ? rrnew/num : 0.f;
#pragma unroll
  for (int u = 0; u < 4; ++u) {
    size_t i = base + u*256 + t;
    PT[i] = rl[u] + beta*pl[u];
  }
  if (t == 0) { RRA[row] = rrnew; PAP[row] = 0.f; }
}

// ---------------- misc ----------------
__global__ __launch_bounds__(256) void zero_kernel(float* __restrict__ p, int n) {
  int idx = blockIdx.x*256 + threadIdx.x;
  if (idx < n) p[idx] = 0.f;
}
__global__ __launch_bounds__(256) void copy_kernel(
    float* __restrict__ dst, const float* __restrict__ src, int n)
{
  size_t idx = (size_t)blockIdx.x*256 + threadIdx.x;
  if (idx < (size_t)n) dst[idx] = src[idx];
}

// ---------------- RoPE (coalesced, de-interleaved QKV) ----------------
// QKV layout per row: [q 0..255 | k 256..511 | v 512..767]; pair rotation is
// in-thread. 0.125*log2e folded into Q. 2 rows per 256-thread block.
__global__ __launch_bounds__(256) void rope_split_kernel(
    const bf16* __restrict__ qkv, const float* __restrict__ enc0,
    const float* __restrict__ enc1, bf16* __restrict__ Qo,
    bf16* __restrict__ Ko)
{
  int t = threadIdx.x;
  int r = blockIdx.x*2 + (t >> 7);
  int c = (t & 127)*2;                    // even col
  int ts = r >> 10, i = r & 1023;
  int d = c & 63;
  const float* enc = (ts < BB) ? enc0 : enc1;
  int s = (ts < BB) ? ts : ts - BB;
  const float* eb = enc + (((size_t)s*2)*KM + i)*HD;
  float2 cs = *(const float2*)&eb[d];
  float2 sn = *(const float2*)&eb[(size_t)KM*HD + d];
  size_t base = (size_t)r*768;
  bf16x2 qv = *(const bf16x2*)&qkv[base + c];
  bf16x2 kv = *(const bf16x2*)&qkv[base + 256 + c];
  float q0 = (float)qv[0], q1 = (float)qv[1];
  float k0 = (float)kv[0], k1 = (float)kv[1];
  float oq0 = q0*cs.x - q1*sn.x, oq1 = q1*cs.y + q0*sn.y;
  float ok0 = k0*cs.x - k1*sn.x, ok1 = k1*cs.y + k0*sn.y;
  size_t o = (size_t)r*DD + c;
  bf16x2 qo = {(bf16)(0.1803368801f*oq0), (bf16)(0.1803368801f*oq1)};
  bf16x2 ko = {(bf16)ok0, (bf16)ok1};
  *(bf16x2*)&Qo[o] = qo;
  *(bf16x2*)&Ko[o] = ko;
}

// ---------------- V -> V^T transpose (per (stream,head)), strided src -------
// src row k of (ts,h): Vin[((size_t)ts*KM + k)*vstride + h*HD + d]
// out: VT[((ts*4+h)*HD + d)*KM + k]
__global__ __launch_bounds__(256) void vt_kernel(
    const bf16* __restrict__ Vin, int vstride, bf16* __restrict__ VT)
{
  __shared__ __align__(16) bf16 Ls[64*72];
  int tid = threadIdx.x;
  int zh = blockIdx.x;
  int ts = zh >> 2, h = zh & 3;
  int k0 = blockIdx.y * 64;
#pragma unroll
  for (int p = 0; p < 2; ++p) {
    int idx = p*256 + tid;
    int kr = idx >> 3, c8 = (idx & 7)*8;
    *(uint4*)&Ls[kr*72 + c8] =
      *(const uint4*)&Vin[((size_t)ts*KM + k0 + kr)*vstride + h*HD + c8];
  }
  __syncthreads();
#pragma unroll
  for (int p = 0; p < 2; ++p) {
    int idx = p*256 + tid;
    int dr = idx >> 3, k8 = (idx & 7)*8;
    bf16 tmp[8] __attribute__((aligned(16)));
#pragma unroll
    for (int j = 0; j < 8; ++j) tmp[j] = Ls[(k8+j)*72 + dr];
    *(uint4*)&VT[((size_t)zh*HD + dr)*KM + k0 + k8] = *(uint4*)tmp;
  }
}

// ---------------- MFMA flash attention body (S^T scheme, V^T input) ----------
// LDS tiles use the SWZ xor-swizzle: conflict-free AND 16B-aligned.
__device__ __forceinline__ void mha_body(
    const bf16* __restrict__ Qg, const bf16* __restrict__ Kg,
    const bf16* __restrict__ VTg, bf16* __restrict__ Og,
    size_t qkbase, size_t obase, size_t vbase, int qkstride,
    int q0, int tid, bf16* Qs, bf16* Ks, bf16* Vt)
{
  int lane = tid & 63, w = tid >> 6;
  int lm = lane & 15, lq = lane >> 4;
#pragma unroll
  for (int p = 0; p < 2; ++p) {
    int idx = p*256 + tid;
    int row = idx >> 3, c8 = (idx & 7)*8;
    *(uint4*)&Qs[SWZ(row, c8)] =
      *(const uint4*)&Qg[qkbase + (size_t)(q0+row)*qkstride + c8];
  }
  __syncthreads();
  bf16x8 qa0 = *(bf16x8*)&Qs[SWZ(w*16 + lm, lq*8)];
  bf16x8 qa1 = *(bf16x8*)&Qs[SWZ(w*16 + lm, 32 + lq*8)];
  float m_ = -1e30f, l_ = 0.f;
  floatx4 oacc[4];
#pragma unroll
  for (int db = 0; db < 4; ++db) oacc[db] = (floatx4){0.f,0.f,0.f,0.f};

  for (int kt = 0; kt < KM; kt += 64) {
    __syncthreads();
#pragma unroll
    for (int p = 0; p < 2; ++p) {
      int idx = p*256 + tid;
      int row = idx >> 3, c8 = (idx & 7)*8;
      *(uint4*)&Ks[SWZ(row, c8)] =
        *(const uint4*)&Kg[qkbase + (size_t)(kt+row)*qkstride + c8];
      *(uint4*)&Vt[SWZ(row, c8)] =
        *(const uint4*)&VTg[vbase + (size_t)row*KM + kt + c8];
    }
    __syncthreads();
    floatx4 st[4];
#pragma unroll
    for (int kb = 0; kb < 4; ++kb) {
      bf16x8 a0 = *(bf16x8*)&Ks[SWZ(kb*16 + lm, lq*8)];
      bf16x8 a1 = *(bf16x8*)&Ks[SWZ(kb*16 + lm, 32 + lq*8)];
      floatx4 acc = (floatx4){0.f,0.f,0.f,0.f};
      acc = MFMA16(a0, qa0, acc);
      acc = MFMA16(a1, qa1, acc);
      st[kb] = acc;
    }
    float mx = -1e30f;
#pragma unroll
    for (int kb = 0; kb < 4; ++kb)
#pragma unroll
      for (int r = 0; r < 4; ++r) mx = fmaxf(mx, st[kb][r]);
    mx = fmaxf(mx, __shfl_xor(mx, 16));
    mx = fmaxf(mx, __shfl_xor(mx, 32));
    if (__ballot(mx > m_)) {
      float mn = fmaxf(m_, mx);
      float al = exp2f(m_ - mn);
      m_ = mn;
      l_ *= al;
#pragma unroll
      for (int db = 0; db < 4; ++db) {
        oacc[db][0] *= al; oacc[db][1] *= al;
        oacc[db][2] *= al; oacc[db][3] *= al;
      }
    }
    float ssum = 0.f;
#pragma unroll
    for (int kb = 0; kb < 4; ++kb)
#pragma unroll
      for (int r = 0; r < 4; ++r) {
        float p = exp2f(st[kb][r] - m_);
        st[kb][r] = p;
        ssum += p;
      }
    ssum += __shfl_xor(ssum, 16);
    ssum += __shfl_xor(ssum, 32);
    l_ += ssum;
#pragma unroll
    for (int kb = 0; kb < 4; ++kb) {
      short4v pb = pack4(st[kb][0], st[kb][1], st[kb][2], st[kb][3]);
#pragma unroll
      for (int db = 0; db < 4; ++db) {
        short4v va = *(const short4v*)&Vt[SWZ(db*16 + lm, kb*16 + lq*4)];
        oacc[db] = MFMA1K(va, pb, oacc[db]);
      }
    }
  }
  float inv = 1.f / l_;
  int q = q0 + w*16 + lm;
#pragma unroll
  for (int db = 0; db < 4; ++db) {
    bf16x4 o4 = { (bf16)(oacc[db][0]*inv), (bf16)(oacc[db][1]*inv),
                  (bf16)(oacc[db][2]*inv), (bf16)(oacc[db][3]*inv) };
    *(bf16x4*)&Og[obase + (size_t)q*DD + db*16 + lq*4] = o4;
  }
}

// self attention: grid (zh=64, qtile=16); Q/K row stride 256
__global__ __launch_bounds__(256) void mha_kernel(
    const bf16* __restrict__ Qg, const bf16* __restrict__ Kg,
    const bf16* __restrict__ VTg, bf16* __restrict__ Og)
{
  __shared__ __align__(16) bf16 Qs[64*64];
  __shared__ __align__(16) bf16 Ks[64*64];
  __shared__ __align__(16) bf16 Vt[64*64];
  int zh = blockIdx.x;
  int z = zh >> 2, h = zh & 3;
  size_t base = ((size_t)z*KM)*DD + (size_t)h*HD;
  size_t vbase = (size_t)zh*HD*KM;
  mha_body(Qg, Kg, VTg, Og, base, base, vbase, DD,
           blockIdx.y*64, threadIdx.x, Qs, Ks, Vt);
}

// cross attention, both directions: grid (zh=32, qtile=16, dir=2)
// Q/K live in QKV2 (row stride 512, q at col 0..255, v projected separately)
__global__ __launch_bounds__(256) void mha_cross_kernel(
    const bf16* __restrict__ QKV2, const bf16* __restrict__ VT2,
    bf16* __restrict__ ATTO2)
{
  __shared__ __align__(16) bf16 Qs[64*64];
  __shared__ __align__(16) bf16 Ks[64*64];
  __shared__ __align__(16) bf16 Vt[64*64];
  int dir = blockIdx.z;
  const bf16* Qg  = QKV2 + (dir ? (size_t)BN*512 : 0);
  const bf16* Kg  = QKV2 + (dir ? 0 : (size_t)BN*512);
  const bf16* VTg = VT2  + (dir ? 0 : (size_t)32*HD*KM);
  bf16*       Og  = ATTO2 + (dir ? (size_t)BN*DD : 0);
  int zh = blockIdx.x;
  int z = zh >> 2, h = zh & 3;
  size_t qkbase = ((size_t)z*KM)*512 + (size_t)h*HD;
  size_t obase  = ((size_t)z*KM)*DD  + (size_t)h*HD;
  size_t vbase  = (size_t)zh*HD*KM;
  mha_body(Qg, Kg, VTg, Og, qkbase, obase, vbase, 512,
           blockIdx.y*64, threadIdx.x, Qs, Ks, Vt);
}

// ---------------- in-place LayerNorm + exact GELU (bf16, width 512) --------
__global__ __launch_bounds__(256) void ln_gelu_kernel(
    bf16* __restrict__ Hb, const float* __restrict__ g,
    const float* __restrict__ be)
{
  __shared__ float red[256];
  int r = blockIdx.x, t = threadIdx.x;
  bf16x2 hv = *(bf16x2*)&Hb[(size_t)r*512 + 2*t];
  float x0 = (float)hv[0], x1 = (float)hv[1];
  red[t] = x0 + x1; __syncthreads();
  for (int s2 = 128; s2 > 0; s2 >>= 1) { if (t < s2) red[t] += red[t+s2]; __syncthreads(); }
  float mu = red[0] * (1.f/512.f); __syncthreads();
  float d0 = x0 - mu, d1 = x1 - mu;
  red[t] = d0*d0 + d1*d1; __syncthreads();
  for (int s2 = 128; s2 > 0; s2 >>= 1) { if (t < s2) red[t] += red[t+s2]; __syncthreads(); }
  float rstd = rsqrtf(red[0]*(1.f/512.f) + 1e-5f);
  float2 gv = *(const float2*)&g[2*t];
  float2 bv = *(const float2*)&be[2*t];
  float h0 = d0*rstd*gv.x + bv.x;
  float h1 = d1*rstd*gv.y + bv.y;
  h0 = 0.5f*h0*(1.f + erff(h0*0.70710678118f));
  h1 = 0.5f*h1*(1.f + erff(h1*0.70710678118f));
  bf16x2 ov = { (bf16)h0, (bf16)h1 };
  *(bf16x2*)&Hb[(size_t)r*512 + 2*t] = ov;
}

// ---------------- final head 2 ----------------
__global__ __launch_bounds__(256) void head2_kernel(
    const float* __restrict__ Hb, const float* __restrict__ w,
    const float* __restrict__ b, float* __restrict__ out)
{
  int r = blockIdx.x*256 + threadIdx.x;
  float acc = b[0];
#pragma unroll
  for (int k = 0; k < 64; ++k) acc += Hb[(size_t)r*64 + k]*w[k];
  out[r] = 1.f/(1.f + expf(-acc));
}

extern "C" void kernel_launch(void* const* d_in, const int* in_sizes, int n_in,
                              void* d_out, int out_size, void* d_ws, size_t ws_size,
                              hipStream_t stream)
{
  (void)in_sizes; (void)n_in; (void)out_size; (void)ws_size;
  const float* fa      = (const float*)d_in[0];
  const float* fb      = (const float*)d_in[1];
  const int*   matches = (const int*)d_in[2];
  const float* ka      = (const float*)d_in[3];
  const float* kb      = (const float*)d_in[4];
  const float* lam     = (const float*)d_in[5];
  const float* beta    = (const float*)d_in[6];
  const float* Wr      = (const float*)d_in[7];
  const float* pW1     = (const float*)d_in[8];
  const float* pb1     = (const float*)d_in[9];
  const float* pW2     = (const float*)d_in[10];
  const float* pb2     = (const float*)d_in[11];
  const float* sWqkv   = (const float*)d_in[12];
  const float* sbqkv   = (const float*)d_in[13];
  const float* sWo     = (const float*)d_in[14];
  const float* sbo     = (const float*)d_in[15];
  const float* sW1     = (const float*)d_in[16];
  const float* sb1     = (const float*)d_in[17];
  const float* sg      = (const float*)d_in[18];
  const float* sbe     = (const float*)d_in[19];
  const float* sW2     = (const float*)d_in[20];
  const float* sb2     = (const float*)d_in[21];
  const float* cWqk    = (const float*)d_in[22];
  const float* cbqk    = (const float*)d_in[23];
  const float* cWv     = (const float*)d_in[24];
  const float* cbv     = (const float*)d_in[25];
  const float* cWo     = (const float*)d_in[26];
  const float* cbo     = (const float*)d_in[27];
  const float* cW1     = (const float*)d_in[28];
  const float* cb1     = (const float*)d_in[29];
  const float* cgw     = (const float*)d_in[30];
  const float* cbe     = (const float*)d_in[31];
  const float* cW2     = (const float*)d_in[32];
  const float* cb2     = (const float*)d_in[33];

  char* wsb = (char*)d_ws;
  float* DCAT = (float*)wsb;                      // 16,777,216 B
  float* ENC0 = (float*)(wsb + 16777216);
  float* ENC1 = (float*)(wsb + 20971520);
  float* XY0  = (float*)(wsb + 25165824);
  float* XY1  = (float*)(wsb + 25231360);
  float* ROWS = (float*)(wsb + 25296896);
  float* RRA  = (float*)(wsb + 25329664);
  float* PAP  = (float*)(wsb + 25346048);
  char*  POOL = wsb + 25354240;
  const size_t SLOT = 8388608;
  // CG phase
  bf16*  KMATH = (bf16*)POOL;                    // slots 0-1
  float* FBUF  = (float*)(POOL + 2*SLOT);
  float* PT    = (float*)(POOL + 3*SLOT);
  float* RT    = (float*)(POOL + 4*SLOT);
  float* XT    = (float*)(POOL + 5*SLOT);
  float* APT   = (float*)(POOL + 6*SLOT);
  // transformer phase
  bf16*  QKV   = (bf16*)POOL;                    // slots 0-2 (q|k|v cols)
  bf16*  QR    = (bf16*)(POOL + 3*SLOT);
  bf16*  KR    = (bf16*)(POOL + 4*SLOT);
  bf16*  VTG   = (bf16*)(POOL + 8*SLOT);         // slot 8 (V^T, self)
  bf16*  ATTO  = (bf16*)POOL;                    // slot 0
  bf16*  MSG   = (bf16*)(POOL + 1*SLOT);
  bf16*  H1    = (bf16*)(POOL + 6*SLOT);         // slots 6-7
  bf16*  QKV2  = (bf16*)POOL;                    // slots 0-1 (cross q|v cols)
  bf16*  ATTO2 = (bf16*)(POOL + 2*SLOT);
  bf16*  MSG2  = (bf16*)(POOL + 3*SLOT);
  bf16*  VT2   = (bf16*)(POOL + 4*SLOT);         // slot 4 (V^T, cross)
  bf16*  H1C   = H1;
  float* HBUF  = (float*)POOL;

  const float scq = 0.42466090f;   // 64^-0.25 * sqrt(log2 e)

  // ---- gather / posenc / Kmat ----
  gather_kernel<<<BN, 256, 0, stream>>>(fa, fb, matches, ka, kb, FBUF, XY0, XY1);
  posenc_kernel<<<BN, 64, 0, stream>>>(XY0, Wr, ENC0);
  posenc_kernel<<<BN, 64, 0, stream>>>(XY1, Wr, ENC1);
  kmat_kernel<<<BN, 256, 0, stream>>>(XY0, beta, KMATH, ROWS);

  // ---- CG (transposed state) ----
  zero_kernel<<<24, 256, 0, stream>>>(RRA, 6144);
  tinit_kernel<<<dim3(16,4,BB), 256, 0, stream>>>(FBUF, PT, RT, XT, RRA);
  for (int it = 0; it < CG_ITERS; ++it) {
    mv64_kernel<float,bf16,float><<<dim3(4,16,BB), 256, 0, stream>>>(
        PT, 1024, KMATH, APT, 1024, PT, lam, (const float*)0, PAP,
        262144, 1048576, 262144, 262144);
    cg_update_kernel<<<2048, 256, 0, stream>>>(XT, RT, PT, APT, RRA, PAP);
  }

  // ---- d0 = f_i ; d1 = rownorm(Kmat) @ C ----
  copy_kernel<<<8192, 256, 0, stream>>>(DCAT, FBUF, BN*DD);
  mv64_kernel<bf16,float,float><<<dim3(16,4,BB), 256, 0, stream>>>(
      KMATH, 1024, XT, DCAT + (size_t)BN*DD, 256,
      (const float*)0, (const float*)0, ROWS, (float*)0,
      1048576, 262144, 262144, 0);

  // ---- transformer layers ----
  for (int l = 0; l < NLAYER; ++l) {
    // self block
    mm_kernel<128,1,0,float,float,float,bf16><<<dim3(128,6,1), 256, 0, stream>>>(
        DCAT, (const float*)0, 256, 256, sWqkv + (size_t)l*768*256, sbqkv + l*768,
        (const float*)0, (const float*)0, QKV, 768, 1.f, 1.f, (const float*)0);
    rope_split_kernel<<<8192, 256, 0, stream>>>(QKV, ENC0, ENC1, QR, KR);
    vt_kernel<<<dim3(64,16), 256, 0, stream>>>(QKV + 512, 768, VTG);
    mha_kernel<<<dim3(64,16), 256, 0, stream>>>(QR, KR, VTG, ATTO);
    mm_kernel<64,0,0,bf16,bf16,float,bf16><<<dim3(128,4,1), 256, 0, stream>>>(
        ATTO, (const bf16*)0, 256, 256, sWo + (size_t)l*256*256, sbo + l*256,
        (const float*)0, (const float*)0, MSG, 256, 1.f, 1.f, (const float*)0);
    mm_kernel<128,0,0,float,bf16,float,bf16><<<dim3(128,4,1), 256, 0, stream>>>(
        DCAT, MSG, 256, 512, sW1 + (size_t)l*512*512, sb1 + l*512,
        (const float*)0, (const float*)0, H1, 512, 1.f, 1.f, (const float*)0);
    ln_gelu_kernel<<<N2, 256, 0, stream>>>(H1, sg + l*512, sbe + l*512);
    mm_kernel<64,0,0,bf16,bf16,float,float><<<dim3(128,4,1), 256, 0, stream>>>(
        H1, (const bf16*)0, 512, 512, sW2 + (size_t)l*256*512, sb2 + l*256,
        (const float*)0, (const float*)0, DCAT, 256, 1.f, 1.f, DCAT);
    // cross block: fused qk|v projection into QKV2 (row stride 512)
    mm_kernel<128,0,1,float,float,float,bf16><<<dim3(128,4,1), 256, 0, stream>>>(
        DCAT, (const float*)0, 256, 256, cWqk + (size_t)l*256*256, cbqk + l*256,
        cWv + (size_t)l*256*256, cbv + l*256, QKV2, 512, scq, 1.f,
        (const float*)0);
    vt_kernel<<<dim3(64,16), 256, 0, stream>>>(QKV2 + 256, 512, VT2);
    mha_cross_kernel<<<dim3(32,16,2), 256, 0, stream>>>(QKV2, VT2, ATTO2);
    mm_kernel<64,0,0,bf16,bf16,float,bf16><<<dim3(128,4,1), 256, 0, stream>>>(
        ATTO2, (const bf16*)0, 256, 256, cWo + (size_t)l*256*256, cbo + l*256,
        (const float*)0, (const float*)0, MSG2, 256, 1.f, 1.f, (const float*)0);
    mm_kernel<128,0,0,float,bf16,float,bf16><<<dim3(128,4,1), 256, 0, stream>>>(
        DCAT, MSG2, 256, 512, cW1 + (size_t)l*512*512, cb1 + l*512,
        (const float*)0, (const float*)0, H1C, 512, 1.f, 1.f, (const float*)0);
    ln_gelu_kernel<<<N2, 256, 0, stream>>>(H1C, cgw + l*512, cbe + l*512);
    mm_kernel<64,0,0,bf16,bf16,float,float><<<dim3(128,4,1), 256, 0, stream>>>(
        H1C, (const bf16*)0, 512, 512, cW2 + (size_t)l*256*512, cb2 + l*256,
        (const float*)0, (const float*)0, DCAT, 256, 1.f, 1.f, DCAT);
  }

  // ---- head ----
  gemm_f32_kernel<<<dim3(128,1), 256, 0, stream>>>(DCAT, 256, pW1, pb1, HBUF, 64);
  head2_kernel<<<32, 256, 0, stream>>>(HBUF, pW2, pb2, (float*)d_out);
}